// Round 14
// baseline (452.830 us; speedup 1.0000x reference)
//
#include <hip/hip_runtime.h>
#include <hip/hip_bf16.h>

#define EPSV 1e-5f

typedef __attribute__((ext_vector_type(8))) short short8;
typedef __attribute__((ext_vector_type(4))) float f32x4;

__device__ __forceinline__ float bf2f(short u) {
    union { float f; unsigned v; } x; x.v = ((unsigned)(unsigned short)u) << 16; return x.f;
}
__device__ __forceinline__ short f2bf(float f) {
    union { float f; unsigned v; } x; x.f = f;
    unsigned r = x.v + 0x7FFFu + ((x.v >> 16) & 1u);
    return (short)(r >> 16);
}

#define GLDS(gp, lp) __builtin_amdgcn_global_load_lds( \
    (const __attribute__((address_space(1))) unsigned int*)(gp), \
    (__attribute__((address_space(3))) unsigned int*)(lp), 16, 0, 0)

// Wbig rows 0..383 interleaved: row 2e = bn1-scaled ev_e, row 2e+1 = gate_e @ mpw.
// rows 384..639 Wk@mpw, 640..895 Wv@mpw.
__global__ __launch_bounds__(256) void make_wbig(
    const float* evw, const float* bn1g, const float* bn1b, const float* bn1m, const float* bn1v,
    const float* gatew, const float* gateb, const float* ipw, const float* ipb, const float* mpw,
    short* Wbig, float* biasBig)
{
    __shared__ float w1[256];
    int r = blockIdx.x, c = threadIdx.x;
    if (r < 384 && (r & 1) == 0) {
        int e = r >> 1;
        float s1 = bn1g[e] * rsqrtf(bn1v[e] + EPSV);
        Wbig[r * 256 + c] = f2bf(evw[e * 256 + c] * s1);
        if (c == 0) biasBig[r] = bn1b[e] - bn1m[e] * s1;
    } else {
        const float* src; float bias;
        if (r < 384)      { int e = r >> 1; src = gatew + e * 256; bias = gateb[e]; }
        else if (r < 640) { src = ipw + (256 + (r - 384)) * 256;  bias = ipb[256 + (r - 384)]; }
        else              { src = ipw + (512 + (r - 640)) * 256;  bias = ipb[512 + (r - 640)]; }
        w1[c] = src[c];
        __syncthreads();
        float a = 0.f;
        #pragma unroll 8
        for (int q = 0; q < 256; ++q) a += w1[q] * mpw[q * 256 + c];
        Wbig[r * 256 + c] = f2bf(a);
        if (c == 0) biasBig[r] = bias;
    }
}

// make_wfold + zero_guard fused
__global__ __launch_bounds__(256) void make_wfold(
    const float* outw, const float* g2, const float* b2, const float* m2, const float* v2,
    short* Wfold, float* t2, float* zp)
{
    int f = blockIdx.x;
    if (f >= 192) {
        int blk = f - 192;
        *(f32x4*)(zp + (blk * 256 + threadIdx.x) * 4) = f32x4{0.f, 0.f, 0.f, 0.f};
        return;
    }
    float s2 = g2[f] * rsqrtf(v2[f] + EPSV);
    for (int idx = threadIdx.x; idx < 1728; idx += 256) {
        int e = idx / 9, tap = idx % 9;
        Wfold[(tap * 192 + f) * 192 + e] = f2bf(outw[(f * 192 + e) * 9 + tap] * s2);
    }
    if (threadIdx.x == 0) t2[f] = b2[f] - m2[f] * s2;
}

// make_q + decode_mask fused
__global__ __launch_bounds__(256) void make_q(const float* sq, const float* ipw, const float* ipb,
                                              const void* raw, float* qout, float* maskf)
{
    int t = blockIdx.x;
    if (t == 4) {
        if (threadIdx.x != 0) return;
        const unsigned* w = (const unsigned*)raw;
        const unsigned char* by = (const unsigned char*)raw;
        bool stride4 = true;
        for (int i = 0; i < 4; ++i) {
            unsigned x = w[i];
            if (!(x == 0u || x == 1u || x == 0x3F800000u)) stride4 = false;
        }
        float vals[16];
        if (stride4) { for (int i = 0; i < 16; ++i) vals[i] = (w[i] != 0u) ? 1.f : 0.f; }
        else         { for (int i = 0; i < 16; ++i) vals[i] = (by[i] != 0) ? 1.f : 0.f; }
        for (int tt = 0; tt < 4; ++tt)
            for (int b = 0; b < 4; ++b)
                maskf[tt * 4 + b] = vals[b * 4 + tt];
        return;
    }
    int i = threadIdx.x;
    float a = ipb[i];
    for (int cc = 0; cc < 256; ++cc) a += sq[t * 256 + cc] * ipw[i * 256 + cc];
    qout[t * 256 + i] = a * 0.125f;
}

__global__ __launch_bounds__(256) void transpose_mem(const float* mem, short* memT)
{
    __shared__ float tile[64][65];
    int hw0 = blockIdx.x * 64, c0 = blockIdx.y * 64, b = blockIdx.z;
    const float* src = mem + (size_t)(b * 256 + c0) * 16384 + hw0;
    #pragma unroll
    for (int j = 0; j < 16; ++j) {
        int idx = threadIdx.x + j * 256;
        int r = idx >> 6, wcol = idx & 63;
        tile[r][wcol] = src[(size_t)r * 16384 + wcol];
    }
    __syncthreads();
    short* dst = memT + (size_t)(b * 16384 + hw0) * 256 + c0;
    #pragma unroll
    for (int j = 0; j < 16; ++j) {
        int idx = threadIdx.x + j * 256;
        int r = idx >> 6, wcol = idx & 63;
        dst[(size_t)r * 256 + wcol] = f2bf(tile[wcol][r]);
    }
}

// big_gemm v4: GLDS staging + fused epilogue -> P2 planes + KV.
__global__ __launch_bounds__(256) void big_gemm(const short* memT, const short* Wbig,
                                                const float* biasBig, short* P2, short* KV)
{
    __shared__ __align__(16) short As[128 * 64];
    __shared__ __align__(16) short Bs[128 * 64];
    int tid = threadIdx.x, lane = tid & 63, wid = tid >> 6;
    int hw0 = blockIdx.x * 128, n0 = blockIdx.y * 128, b = blockIdx.z;
    int wm = wid & 1, wn = wid >> 1;
    f32x4 acc[4][4];
    #pragma unroll
    for (int i = 0; i < 4; ++i)
        #pragma unroll
        for (int j = 0; j < 4; ++j)
            #pragma unroll
            for (int r = 0; r < 4; ++r) acc[i][j][r] = 0.f;

    int r8 = lane >> 3, c8 = lane & 7;
    int cs = c8 ^ r8;
    const short* Abase = memT + (size_t)(b * 16384 + hw0) * 256 + cs * 8;
    const short* Bbase = Wbig + (size_t)n0 * 256 + cs * 8;

    for (int kk = 0; kk < 256; kk += 64) {
        #pragma unroll
        for (int s = 0; s < 4; ++s) {
            int seg = wid * 4 + s;
            int row = seg * 8 + r8;
            GLDS(Abase + (size_t)row * 256 + kk, As + seg * 512);
            GLDS(Bbase + (size_t)row * 256 + kk, Bs + seg * 512);
        }
        __syncthreads();
        #pragma unroll
        for (int ks = 0; ks < 2; ++ks) {
            short8 af[4], bfr[4];
            #pragma unroll
            for (int mt = 0; mt < 4; ++mt) {
                int row = wm * 64 + mt * 16 + (lane & 15);
                af[mt] = *(const short8*)((char*)As + ((row * 128 + ks * 64 + (lane >> 4) * 16) ^ ((row & 7) << 4)));
            }
            #pragma unroll
            for (int nt = 0; nt < 4; ++nt) {
                int col = wn * 64 + nt * 16 + (lane & 15);
                bfr[nt] = *(const short8*)((char*)Bs + ((col * 128 + ks * 64 + (lane >> 4) * 16) ^ ((col & 7) << 4)));
            }
            #pragma unroll
            for (int mt = 0; mt < 4; ++mt)
                #pragma unroll
                for (int nt = 0; nt < 4; ++nt)
                    acc[mt][nt] = __builtin_amdgcn_mfma_f32_16x16x32_bf16(af[mt], bfr[nt], acc[mt][nt], 0, 0, 0);
        }
        __syncthreads();
    }
    if (n0 < 384) {
        #pragma unroll
        for (int nt = 0; nt < 4; ++nt) {
            int col = n0 + wn * 64 + nt * 16 + (lane & 15);
            float bias = biasBig[col];
            int e = col >> 1;
            short* pplane = P2 + ((size_t)(b * 24 + (e >> 3)) * 16384) * 8 + (e & 7);
            #pragma unroll
            for (int mt = 0; mt < 4; ++mt) {
                int hwbase = hw0 + wm * 64 + mt * 16 + (lane >> 4) * 4;
                #pragma unroll
                for (int r = 0; r < 4; ++r) {
                    float v = acc[mt][nt][r] + bias;
                    float p = __shfl_xor(v, 1);
                    if ((lane & 1) == 0) {
                        float se = 1.f / (1.f + __expf(-v));
                        float sg = 1.f / (1.f + __expf(-p));
                        pplane[(size_t)(hwbase + r) * 8] = f2bf(v * se * sg);
                    }
                }
            }
        }
    } else {
        #pragma unroll
        for (int nt = 0; nt < 4; ++nt) {
            int col = n0 + wn * 64 + nt * 16 + (lane & 15);
            float bias = biasBig[col];
            int kcol = col - 384;
            #pragma unroll
            for (int mt = 0; mt < 4; ++mt) {
                int hwbase = hw0 + wm * 64 + mt * 16 + (lane >> 4) * 4;
                #pragma unroll
                for (int r = 0; r < 4; ++r)
                    KV[(size_t)(b * 16384 + hwbase + r) * 512 + kcol] = f2bf(acc[mt][nt][r] + bias);
            }
        }
    }
}

__global__ __launch_bounds__(256) void attn_a(const short* KV, const float* qs,
                                              float* Opart, float* Lpart)
{
    __shared__ float qlds[256];
    __shared__ float Esm[4 * 512];
    __shared__ float wl[4][4];
    __shared__ short vlds[128 * 72];
    int tid = threadIdx.x, lane = tid & 63, wid = tid >> 6;
    int chunk = blockIdx.x, n = blockIdx.y, b = blockIdx.z;
    int s0 = chunk * 512;
    qlds[tid] = qs[(tid >> 6) * 256 + n * 64 + (tid & 63)];
    __syncthreads();
    float lp[4] = {0.f, 0.f, 0.f, 0.f};
    #pragma unroll
    for (int half = 0; half < 2; ++half) {
        int s = s0 + half * 256 + tid;
        const short* kb = KV + (size_t)(b * 16384 + s) * 512 + n * 64;
        float sc[4] = {0.f, 0.f, 0.f, 0.f};
        #pragma unroll
        for (int i = 0; i < 8; ++i) {
            short8 k8 = *(const short8*)(kb + i * 8);
            #pragma unroll
            for (int j = 0; j < 8; ++j) {
                float kf = bf2f(k8[j]);
                #pragma unroll
                for (int t = 0; t < 4; ++t) sc[t] += kf * qlds[t * 64 + i * 8 + j];
            }
        }
        #pragma unroll
        for (int t = 0; t < 4; ++t) {
            float e = __expf(sc[t]);
            Esm[t * 512 + half * 256 + tid] = e;
            lp[t] += e;
        }
    }
    #pragma unroll
    for (int t = 0; t < 4; ++t) {
        float v = lp[t];
        for (int off = 32; off; off >>= 1) v += __shfl_down(v, off);
        if (lane == 0) wl[wid][t] = v;
    }
    __syncthreads();
    if (tid < 4)
        Lpart[((b * 4 + n) * 32 + chunk) * 4 + tid] = wl[0][tid] + wl[1][tid] + wl[2][tid] + wl[3][tid];

    float o = 0.f;
    int tt = tid >> 6, d = tid & 63;
    for (int sub = 0; sub < 4; ++sub) {
        __syncthreads();
        #pragma unroll
        for (int j = 0; j < 4; ++j) {
            int idx = tid + j * 256;
            int r = idx >> 3, c16 = idx & 7;
            const short* vb = KV + (size_t)(b * 16384 + s0 + sub * 128 + r) * 512 + 256 + n * 64 + c16 * 8;
            *(short8*)((char*)vlds + r * 144 + c16 * 16) = *(const short8*)vb;
        }
        __syncthreads();
        #pragma unroll 8
        for (int r = 0; r < 128; ++r)
            o += Esm[tt * 512 + sub * 128 + r] * bf2f(vlds[r * 72 + d]);
    }
    Opart[(size_t)((b * 4 + n) * 32 + chunk) * 256 + tid] = o;
}

__global__ __launch_bounds__(256) void attn_b(const float* Opart, const float* Lpart, float* attended)
{
    int bn = blockIdx.x;
    int tid = threadIdx.x, t = tid >> 6, d = tid & 63;
    float o = 0.f, l = 0.f;
    for (int c = 0; c < 32; ++c) o += Opart[(size_t)(bn * 32 + c) * 256 + tid];
    for (int c = 0; c < 32; ++c) l += Lpart[(bn * 32 + c) * 4 + t];
    int b = bn >> 2, n = bn & 3;
    attended[(t * 4 + b) * 256 + n * 64 + d] = o / l;
}

__global__ __launch_bounds__(256) void film_kernel(const float* attended, const float* opw, const float* opb,
                                                   const float* fw, const float* fb,
                                                   float* Afilm, float* Bfilm)
{
    __shared__ float att[256], st[256];
    int tb = blockIdx.x, tid = threadIdx.x;
    att[tid] = attended[tb * 256 + tid];
    __syncthreads();
    float a = opb[tid];
    for (int j = 0; j < 256; ++j) a += att[j] * opw[tid * 256 + j];
    st[tid] = a;
    __syncthreads();
    float g1 = fb[tid];
    for (int j = 0; j < 256; ++j) g1 += st[j] * fw[tid * 256 + j];
    if (tid < 192) Afilm[tb * 192 + tid] = 1.f + g1;
    else           Bfilm[tb * 192 + (tid - 192)] = g1;
    if (tid < 128) {
        int jj = 256 + tid;
        float g2 = fb[jj];
        for (int j = 0; j < 256; ++j) g2 += st[j] * fw[jj * 256 + j];
        Bfilm[tb * 192 + (jj - 192)] = g2;
    }
}

__global__ __launch_bounds__(256) void make_w2(const short* Wfold, const float* Afilm, short* W2L)
{
    __shared__ float A[192];
    int tb = blockIdx.x, tap = blockIdx.y;
    if (threadIdx.x < 192) A[threadIdx.x] = Afilm[tb * 192 + threadIdx.x];
    __syncthreads();
    for (int u = threadIdx.x; u < 4608; u += 256) {
        int ec = u / 768, rem = u % 768, f16 = rem >> 6, l = rem & 63;
        int f = f16 * 16 + (l & 15), e0 = ec * 32 + (l >> 4) * 8;
        short8 wv = *(const short8*)(Wfold + (tap * 192 + f) * 192 + e0);
        short8 o;
        #pragma unroll
        for (int j = 0; j < 8; ++j) o[j] = f2bf(bf2f(wv[j]) * A[e0 + j]);
        *(short8*)(W2L + ((((size_t)(tb * 6 + ec) * 9 + tap) * 12 + f16) * 64 + l) * 8) = o;
    }
}

__global__ __launch_bounds__(256) void make_btab(const short* Wfold, const float* Bfilm, float* Btab)
{
    __shared__ short Wt[192 * 192];
    __shared__ float Bv[16][192];
    int tap = blockIdx.x, tid = threadIdx.x;
    for (int u = tid; u < 4608; u += 256)
        *(short8*)(Wt + u * 8) = *(const short8*)(Wfold + (size_t)tap * 36864 + u * 8);
    for (int u = tid; u < 3072; u += 256) Bv[u / 192][u % 192] = Bfilm[u];
    __syncthreads();
    for (int o = tid; o < 3072; o += 256) {
        int tb = o / 192, f = o % 192;
        const short* wr = Wt + f * 192;
        float a = 0.f;
        #pragma unroll 8
        for (int e = 0; e < 192; ++e) a += bf2f(wr[e]) * Bv[tb][e];
        Btab[((size_t)tb * 9 + tap) * 192 + f] = a;
    }
}

// conv v12: same as v11 but 3 blocks/CU (6 waves/SIMD). Regs/wave ~108, cap
// floor(2048/6)=341 -> no spill possible. LDS 3x52224 = 156672 <= 163840.
__global__ __launch_bounds__(512, 6) void conv2_kernel(const short* P2, const short* W2L, const float* t2,
                                                       const float* Btab, const float* maskf,
                                                       const short* zp, float* out)
{
    __shared__ __align__(16) short XB[2][12480];   // 12 segs * 130 units * 8 shorts
    __shared__ float biasC[192], cLs[192], cRs[192];
    int tid = threadIdx.x, lane = tid & 63, wid = tid >> 6;
    int fgrp = wid >> 1, whalf = wid & 1;
    int i = blockIdx.x + blockIdx.y * 128;
    int n = (i & 7) * 256 + (i >> 3);              // XCD-chunked remap
    int h = n & 127, tb = n >> 7;
    int b = tb & 3;
    float m = maskf[tb];
    float* obase = out + (size_t)tb * 192 * 16384 + h * 128;
    if (m == 0.f) {
        #pragma unroll
        for (int it = 0; it < 48; ++it) {
            int idx = tid + it * 512;
            int f = idx >> 7, w = idx & 127;
            obase[(size_t)f * 16384 + w] = 0.f;
        }
        return;
    }
    if (tid < 192) {
        const float* T = Btab + (size_t)tb * 1728 + tid;
        float s0 = T[0], s1 = T[192], s2v = T[384], s3 = T[576], s4 = T[768];
        float s5 = T[960], s6 = T[1152], s7 = T[1344], s8 = T[1536];
        float bc = s0 + s1 + s2v + s3 + s4 + s5 + s6 + s7 + s8;
        float l = s0 + s3 + s6, r = s2v + s5 + s8;
        if (h == 0)   { bc -= s0 + s1 + s2v; l -= s0; r -= s2v; }
        if (h == 127) { bc -= s6 + s7 + s8; l -= s6; r -= s8; }
        biasC[tid] = bc; cLs[tid] = l; cRs[tid] = r;
    }
    f32x4 acc[3][4];
    #pragma unroll
    for (int a = 0; a < 3; ++a)
        #pragma unroll
        for (int c = 0; c < 4; ++c)
            #pragma unroll
            for (int r = 0; r < 4; ++r) acc[a][c][r] = 0.f;

    short* buf0 = &XB[0][0];
    short* buf1 = &XB[1][0];

    auto STAGE = [&](short* buf, int ec) {
        #pragma unroll
        for (int s = 0; s < 2; ++s) {
            int seg = wid + s * 8;
            if (seg < 12) {
                int row = seg >> 2, eu = seg & 3;
                int habs = h + row - 1;
                bool hok = (unsigned)habs < 128u;
                const short* plane = P2 + ((size_t)(b * 24 + ec * 4 + eu) * 16384) * 8;
                long hbase = (long)habs * 128 - 1;
                short* ldst = buf + seg * 1040;
                const short* a0 = (hok && lane > 0) ? plane + (hbase + lane) * 8       : zp + lane * 8;
                const short* a1 = hok               ? plane + (hbase + 64 + lane) * 8  : zp + 1024 + lane * 8;
                GLDS(a0, ldst);
                GLDS(a1, ldst + 512);
                if (lane < 2) {
                    const short* a2 = (hok && lane < 1) ? plane + (hbase + 128 + lane) * 8 : zp + 2048 + lane * 8;
                    GLDS(a2, ldst + 1024);
                }
            }
        }
    };
    const short* wbase = W2L + (size_t)tb * 331776 + (fgrp * 3) * 512 + lane * 8;
    int cl = lane & 15, q = lane >> 4;

    STAGE(buf0, 0);
    __syncthreads();
    #pragma unroll
    for (int t = 0; t < 6; ++t) {
        const short* cur = (t & 1) ? buf1 : buf0;
        short* nxt = (t & 1) ? buf0 : buf1;
        if (t < 5) STAGE(nxt, t + 1);

        const short* wec = wbase + (size_t)t * 55296;
        __builtin_amdgcn_s_setprio(1);
        #pragma unroll
        for (int tap = 0; tap < 9; ++tap) {
            int dy = tap / 3, dx = tap % 3;
            short8 af[3];
            #pragma unroll
            for (int ft = 0; ft < 3; ++ft)
                af[ft] = *(const short8*)(wec + tap * 6144 + ft * 512);
            const short* xrow = cur + ((dy * 4 + q) * 130 + whalf * 64 + cl + dx) * 8;
            #pragma unroll
            for (int wt = 0; wt < 4; ++wt) {
                short8 xb = *(const short8*)(xrow + wt * 128);
                #pragma unroll
                for (int ft = 0; ft < 3; ++ft)
                    acc[ft][wt] = __builtin_amdgcn_mfma_f32_16x16x32_bf16(af[ft], xb, acc[ft][wt], 0, 0, 0);
            }
        }
        __builtin_amdgcn_s_setprio(0);
        if (t < 5) __syncthreads();
    }

    #pragma unroll
    for (int ft = 0; ft < 3; ++ft)
        #pragma unroll
        for (int r = 0; r < 4; ++r) {
            int f = fgrp * 48 + ft * 16 + q * 4 + r;
            float bc = biasC[f] + t2[f];
            float lf = cLs[f], rg = cRs[f];
            #pragma unroll
            for (int wt = 0; wt < 4; ++wt) {
                int w = whalf * 64 + wt * 16 + cl;
                float val = acc[ft][wt][r] + bc;
                if (w == 0)   val -= lf;
                if (w == 127) val -= rg;
                obase[(size_t)f * 16384 + w] = val / (1.f + __expf(-val)) * m;
            }
        }
}

// ---- fallback conv (used if ws_size too small for W2L), P2 layout ----
__global__ __launch_bounds__(256) void conv_kernel(const short* P2, const short* Wfold, const float* t2,
                                                   const float* Afilm, const float* Bfilm, const float* maskf,
                                                   float* out)
{
    __shared__ short Xs[3 * 130 * 32];
    __shared__ float Af[192], Bf[192];
    int tid = threadIdx.x, lane = tid & 63, wid = tid >> 6;
    int h = blockIdx.x, tb = blockIdx.y;
    int b = tb & 3;
    float* obase = out + (size_t)tb * 192 * 16384 + h * 128;
    float m = maskf[tb];
    if (m == 0.f) {
        #pragma unroll
        for (int i = 0; i < 96; ++i) {
            int idx = tid + i * 256;
            int f = idx >> 7, w = idx & 127;
            obase[(size_t)f * 16384 + w] = 0.f;
        }
        return;
    }
    if (tid < 192) { Af[tid] = Afilm[tb * 192 + tid]; Bf[tid] = Bfilm[tb * 192 + tid]; }
    f32x4 acc[3][8];
    #pragma unroll
    for (int i = 0; i < 3; ++i)
        #pragma unroll
        for (int j = 0; j < 8; ++j)
            #pragma unroll
            for (int r = 0; r < 4; ++r) acc[i][j][r] = 0.f;
    __syncthreads();

    for (int ec = 0; ec < 6; ++ec) {
        #pragma unroll
        for (int it = 0; it < 7; ++it) {
            int u = tid + it * 256;
            if (u < 1560) {
                int pos = u >> 2, half = u & 3;
                int row = (pos >= 260) ? 2 : (pos >= 130 ? 1 : 0);
                int col = pos - row * 130;
                int habs = h + row - 1;
                int w = col - 1;
                short8 x8 = {0, 0, 0, 0, 0, 0, 0, 0};
                if ((unsigned)habs < 128u && (unsigned)w < 128u) {
                    int e0 = ec * 32 + half * 8;
                    short8 pv = *(const short8*)(P2 + ((size_t)(b * 24 + (e0 >> 3)) * 16384 + habs * 128 + w) * 8);
                    #pragma unroll
                    for (int i = 0; i < 8; ++i)
                        x8[i] = f2bf(bf2f(pv[i]) * Af[e0 + i] + Bf[e0 + i]);
                }
                *(short8*)((char*)Xs + (((row * 130 + col) * 64 + half * 16) ^ ((col & 7) << 4))) = x8;
            }
        }
        __syncthreads();
        #pragma unroll
        for (int tap = 0; tap < 9; ++tap) {
            int dy = tap / 3, dx = tap % 3;
            short8 af[3];
            #pragma unroll
            for (int ft = 0; ft < 3; ++ft) {
                int f = wid * 48 + ft * 16 + (lane & 15);
                af[ft] = *(const short8*)(Wfold + (tap * 192 + f) * 192 + ec * 32 + (lane >> 4) * 8);
            }
            #pragma unroll
            for (int wt = 0; wt < 8; ++wt) {
                int cs = wt * 16 + (lane & 15) + dx;
                short8 bfr = *(const short8*)((char*)Xs + (((dy * 130 + cs) * 64 + (lane >> 4) * 16) ^ ((cs & 7) << 4)));
                #pragma unroll
                for (int ft = 0; ft < 3; ++ft)
                    acc[ft][wt] = __builtin_amdgcn_mfma_f32_16x16x32_bf16(af[ft], bfr, acc[ft][wt], 0, 0, 0);
            }
        }
        __syncthreads();
    }
    #pragma unroll
    for (int ft = 0; ft < 3; ++ft)
        #pragma unroll
        for (int wt = 0; wt < 8; ++wt) {
            int w = wt * 16 + (lane & 15);
            #pragma unroll
            for (int r = 0; r < 4; ++r) {
                int f = wid * 48 + ft * 16 + (lane >> 4) * 4 + r;
                float val = acc[ft][wt][r] + t2[f];
                obase[(size_t)f * 16384 + w] = val / (1.f + __expf(-val)) * m;
            }
        }
}

extern "C" void kernel_launch(void* const* d_in, const int* in_sizes, int n_in,
                              void* d_out, int out_size, void* d_ws, size_t ws_size,
                              hipStream_t stream)
{
    (void)in_sizes; (void)n_in; (void)out_size;
    const float* memory = (const float*)d_in[0];
    const void*  mask   = d_in[1];
    const float* sq     = (const float*)d_in[2];
    const float* mpw    = (const float*)d_in[3];
    const float* ipw    = (const float*)d_in[4];
    const float* ipb    = (const float*)d_in[5];
    const float* opw    = (const float*)d_in[6];
    const float* opb    = (const float*)d_in[7];
    const float* evw    = (const float*)d_in[8];
    const float* bn1g   = (const float*)d_in[9];
    const float* bn1b   = (const float*)d_in[10];
    const float* bn1m   = (const float*)d_in[11];
    const float* bn1v   = (const float*)d_in[12];
    const float* gatew  = (const float*)d_in[13];
    const float* gateb  = (const float*)d_in[14];
    const float* filmw  = (const float*)d_in[15];
    const float* filmb  = (const float*)d_in[16];
    const float* outw   = (const float*)d_in[17];
    const float* bn2g   = (const float*)d_in[18];
    const float* bn2b   = (const float*)d_in[19];
    const float* bn2m   = (const float*)d_in[20];
    const float* bn2v   = (const float*)d_in[21];

    char* ws = (char*)d_ws;
    short* P        = (short*)(ws + 65536);            // 25165824 B (P2: [b][24][16384][8])
    short* Wbig     = (short*)(ws + 25296896);         // 458752 B
    float* biasBig  = (float*)(ws + 25755648);         // 3584 B
    short* Wfold    = (short*)(ws + 25759232);         // 663552 B
    float* t2       = (float*)(ws + 26422784);         // 768 B
    float* qs       = (float*)(ws + 26423552);         // 4096 B
    float* attended = (float*)(ws + 26427648);         // 4096 B
    float* Afilm    = (float*)(ws + 26431744);         // 12288 B
    float* Bfilm    = (float*)(ws + 26444032);         // 12288 B
    float* maskf    = (float*)(ws + 26456320);         // 256 B
    float* Lpart    = (float*)(ws + 26456576);         // 8192 B
    short* W2       = (short*)(ws + 26464768);         // 10616832 B (W2L)
    float* Btab     = (float*)(ws + 37081600);         // 110592 B
    const size_t WS_NEED = 37204480;

    char* ob = (char*)d_out;
    short* KV     = (short*)(ob);                      // 67108864 B
    short* memT   = (short*)(ob + 67108864);           // 33554432 B
    float* Opart  = (float*)(ob + 100663296);          // 524288 B

    make_wbig<<<896, 256, 0, stream>>>(evw, bn1g, bn1b, bn1m, bn1v, gatew, gateb, ipw, ipb, mpw, Wbig, biasBig);
    make_wfold<<<208, 256, 0, stream>>>(outw, bn2g, bn2b, bn2m, bn2v, Wfold, t2, (float*)ws);
    make_q<<<5, 256, 0, stream>>>(sq, ipw, ipb, mask, qs, maskf);
    transpose_mem<<<dim3(256, 4, 4), 256, 0, stream>>>(memory, memT);
    big_gemm<<<dim3(128, 7, 4), 256, 0, stream>>>(memT, Wbig, biasBig, P, KV);
    attn_a<<<dim3(32, 4, 4), 256, 0, stream>>>(KV, qs, Opart, Lpart);
    attn_b<<<16, 256, 0, stream>>>(Opart, Lpart, attended);
    film_kernel<<<16, 256, 0, stream>>>(attended, opw, opb, filmw, filmb, Afilm, Bfilm);

    if (ws_size >= WS_NEED) {
        make_w2<<<dim3(16, 9), 256, 0, stream>>>(Wfold, Afilm, W2);
        make_btab<<<9, 256, 0, stream>>>(Wfold, Bfilm, Btab);
        conv2_kernel<<<dim3(128, 16), 512, 0, stream>>>(P, W2, t2, Btab, maskf, (const short*)ws, (float*)d_out);
    } else {
        conv_kernel<<<dim3(128, 16), 256, 0, stream>>>(P, Wfold, t2, Afilm, Bfilm, maskf, (float*)d_out);
    }
}

// Round 15
// 365.408 us; speedup vs baseline: 1.2392x; 1.2392x over previous
//
#include <hip/hip_runtime.h>
#include <hip/hip_bf16.h>

#define EPSV 1e-5f

typedef __attribute__((ext_vector_type(8))) short short8;
typedef __attribute__((ext_vector_type(4))) float f32x4;

__device__ __forceinline__ float bf2f(short u) {
    union { float f; unsigned v; } x; x.v = ((unsigned)(unsigned short)u) << 16; return x.f;
}
__device__ __forceinline__ short f2bf(float f) {
    union { float f; unsigned v; } x; x.f = f;
    unsigned r = x.v + 0x7FFFu + ((x.v >> 16) & 1u);
    return (short)(r >> 16);
}

#define GLDS(gp, lp) __builtin_amdgcn_global_load_lds( \
    (const __attribute__((address_space(1))) unsigned int*)(gp), \
    (__attribute__((address_space(3))) unsigned int*)(lp), 16, 0, 0)

// Wbig rows 0..383 interleaved: row 2e = bn1-scaled ev_e, row 2e+1 = gate_e @ mpw.
// rows 384..639 Wk@mpw, 640..895 Wv@mpw.
__global__ __launch_bounds__(256) void make_wbig(
    const float* evw, const float* bn1g, const float* bn1b, const float* bn1m, const float* bn1v,
    const float* gatew, const float* gateb, const float* ipw, const float* ipb, const float* mpw,
    short* Wbig, float* biasBig)
{
    __shared__ float w1[256];
    int r = blockIdx.x, c = threadIdx.x;
    if (r < 384 && (r & 1) == 0) {
        int e = r >> 1;
        float s1 = bn1g[e] * rsqrtf(bn1v[e] + EPSV);
        Wbig[r * 256 + c] = f2bf(evw[e * 256 + c] * s1);
        if (c == 0) biasBig[r] = bn1b[e] - bn1m[e] * s1;
    } else {
        const float* src; float bias;
        if (r < 384)      { int e = r >> 1; src = gatew + e * 256; bias = gateb[e]; }
        else if (r < 640) { src = ipw + (256 + (r - 384)) * 256;  bias = ipb[256 + (r - 384)]; }
        else              { src = ipw + (512 + (r - 640)) * 256;  bias = ipb[512 + (r - 640)]; }
        w1[c] = src[c];
        __syncthreads();
        float a = 0.f;
        #pragma unroll 8
        for (int q = 0; q < 256; ++q) a += w1[q] * mpw[q * 256 + c];
        Wbig[r * 256 + c] = f2bf(a);
        if (c == 0) biasBig[r] = bias;
    }
}

// make_wfold + zero_guard fused
__global__ __launch_bounds__(256) void make_wfold(
    const float* outw, const float* g2, const float* b2, const float* m2, const float* v2,
    short* Wfold, float* t2, float* zp)
{
    int f = blockIdx.x;
    if (f >= 192) {
        int blk = f - 192;
        *(f32x4*)(zp + (blk * 256 + threadIdx.x) * 4) = f32x4{0.f, 0.f, 0.f, 0.f};
        return;
    }
    float s2 = g2[f] * rsqrtf(v2[f] + EPSV);
    for (int idx = threadIdx.x; idx < 1728; idx += 256) {
        int e = idx / 9, tap = idx % 9;
        Wfold[(tap * 192 + f) * 192 + e] = f2bf(outw[(f * 192 + e) * 9 + tap] * s2);
    }
    if (threadIdx.x == 0) t2[f] = b2[f] - m2[f] * s2;
}

// make_q + decode_mask fused
__global__ __launch_bounds__(256) void make_q(const float* sq, const float* ipw, const float* ipb,
                                              const void* raw, float* qout, float* maskf)
{
    int t = blockIdx.x;
    if (t == 4) {
        if (threadIdx.x != 0) return;
        const unsigned* w = (const unsigned*)raw;
        const unsigned char* by = (const unsigned char*)raw;
        bool stride4 = true;
        for (int i = 0; i < 4; ++i) {
            unsigned x = w[i];
            if (!(x == 0u || x == 1u || x == 0x3F800000u)) stride4 = false;
        }
        float vals[16];
        if (stride4) { for (int i = 0; i < 16; ++i) vals[i] = (w[i] != 0u) ? 1.f : 0.f; }
        else         { for (int i = 0; i < 16; ++i) vals[i] = (by[i] != 0) ? 1.f : 0.f; }
        for (int tt = 0; tt < 4; ++tt)
            for (int b = 0; b < 4; ++b)
                maskf[tt * 4 + b] = vals[b * 4 + tt];
        return;
    }
    int i = threadIdx.x;
    float a = ipb[i];
    for (int cc = 0; cc < 256; ++cc) a += sq[t * 256 + cc] * ipw[i * 256 + cc];
    qout[t * 256 + i] = a * 0.125f;
}

__global__ __launch_bounds__(256) void transpose_mem(const float* mem, short* memT)
{
    __shared__ float tile[64][65];
    int hw0 = blockIdx.x * 64, c0 = blockIdx.y * 64, b = blockIdx.z;
    const float* src = mem + (size_t)(b * 256 + c0) * 16384 + hw0;
    #pragma unroll
    for (int j = 0; j < 16; ++j) {
        int idx = threadIdx.x + j * 256;
        int r = idx >> 6, wcol = idx & 63;
        tile[r][wcol] = src[(size_t)r * 16384 + wcol];
    }
    __syncthreads();
    short* dst = memT + (size_t)(b * 16384 + hw0) * 256 + c0;
    #pragma unroll
    for (int j = 0; j < 16; ++j) {
        int idx = threadIdx.x + j * 256;
        int r = idx >> 6, wcol = idx & 63;
        dst[(size_t)r * 256 + wcol] = f2bf(tile[wcol][r]);
    }
}

// big_gemm v4: GLDS staging + fused epilogue -> P2 planes + KV.
__global__ __launch_bounds__(256) void big_gemm(const short* memT, const short* Wbig,
                                                const float* biasBig, short* P2, short* KV)
{
    __shared__ __align__(16) short As[128 * 64];
    __shared__ __align__(16) short Bs[128 * 64];
    int tid = threadIdx.x, lane = tid & 63, wid = tid >> 6;
    int hw0 = blockIdx.x * 128, n0 = blockIdx.y * 128, b = blockIdx.z;
    int wm = wid & 1, wn = wid >> 1;
    f32x4 acc[4][4];
    #pragma unroll
    for (int i = 0; i < 4; ++i)
        #pragma unroll
        for (int j = 0; j < 4; ++j)
            #pragma unroll
            for (int r = 0; r < 4; ++r) acc[i][j][r] = 0.f;

    int r8 = lane >> 3, c8 = lane & 7;
    int cs = c8 ^ r8;
    const short* Abase = memT + (size_t)(b * 16384 + hw0) * 256 + cs * 8;
    const short* Bbase = Wbig + (size_t)n0 * 256 + cs * 8;

    for (int kk = 0; kk < 256; kk += 64) {
        #pragma unroll
        for (int s = 0; s < 4; ++s) {
            int seg = wid * 4 + s;
            int row = seg * 8 + r8;
            GLDS(Abase + (size_t)row * 256 + kk, As + seg * 512);
            GLDS(Bbase + (size_t)row * 256 + kk, Bs + seg * 512);
        }
        __syncthreads();
        #pragma unroll
        for (int ks = 0; ks < 2; ++ks) {
            short8 af[4], bfr[4];
            #pragma unroll
            for (int mt = 0; mt < 4; ++mt) {
                int row = wm * 64 + mt * 16 + (lane & 15);
                af[mt] = *(const short8*)((char*)As + ((row * 128 + ks * 64 + (lane >> 4) * 16) ^ ((row & 7) << 4)));
            }
            #pragma unroll
            for (int nt = 0; nt < 4; ++nt) {
                int col = wn * 64 + nt * 16 + (lane & 15);
                bfr[nt] = *(const short8*)((char*)Bs + ((col * 128 + ks * 64 + (lane >> 4) * 16) ^ ((col & 7) << 4)));
            }
            #pragma unroll
            for (int mt = 0; mt < 4; ++mt)
                #pragma unroll
                for (int nt = 0; nt < 4; ++nt)
                    acc[mt][nt] = __builtin_amdgcn_mfma_f32_16x16x32_bf16(af[mt], bfr[nt], acc[mt][nt], 0, 0, 0);
        }
        __syncthreads();
    }
    if (n0 < 384) {
        #pragma unroll
        for (int nt = 0; nt < 4; ++nt) {
            int col = n0 + wn * 64 + nt * 16 + (lane & 15);
            float bias = biasBig[col];
            int e = col >> 1;
            short* pplane = P2 + ((size_t)(b * 24 + (e >> 3)) * 16384) * 8 + (e & 7);
            #pragma unroll
            for (int mt = 0; mt < 4; ++mt) {
                int hwbase = hw0 + wm * 64 + mt * 16 + (lane >> 4) * 4;
                #pragma unroll
                for (int r = 0; r < 4; ++r) {
                    float v = acc[mt][nt][r] + bias;
                    float p = __shfl_xor(v, 1);
                    if ((lane & 1) == 0) {
                        float se = 1.f / (1.f + __expf(-v));
                        float sg = 1.f / (1.f + __expf(-p));
                        pplane[(size_t)(hwbase + r) * 8] = f2bf(v * se * sg);
                    }
                }
            }
        }
    } else {
        #pragma unroll
        for (int nt = 0; nt < 4; ++nt) {
            int col = n0 + wn * 64 + nt * 16 + (lane & 15);
            float bias = biasBig[col];
            int kcol = col - 384;
            #pragma unroll
            for (int mt = 0; mt < 4; ++mt) {
                int hwbase = hw0 + wm * 64 + mt * 16 + (lane >> 4) * 4;
                #pragma unroll
                for (int r = 0; r < 4; ++r)
                    KV[(size_t)(b * 16384 + hwbase + r) * 512 + kcol] = f2bf(acc[mt][nt][r] + bias);
            }
        }
    }
}

__global__ __launch_bounds__(256) void attn_a(const short* KV, const float* qs,
                                              float* Opart, float* Lpart)
{
    __shared__ float qlds[256];
    __shared__ float Esm[4 * 512];
    __shared__ float wl[4][4];
    __shared__ short vlds[128 * 72];
    int tid = threadIdx.x, lane = tid & 63, wid = tid >> 6;
    int chunk = blockIdx.x, n = blockIdx.y, b = blockIdx.z;
    int s0 = chunk * 512;
    qlds[tid] = qs[(tid >> 6) * 256 + n * 64 + (tid & 63)];
    __syncthreads();
    float lp[4] = {0.f, 0.f, 0.f, 0.f};
    #pragma unroll
    for (int half = 0; half < 2; ++half) {
        int s = s0 + half * 256 + tid;
        const short* kb = KV + (size_t)(b * 16384 + s) * 512 + n * 64;
        float sc[4] = {0.f, 0.f, 0.f, 0.f};
        #pragma unroll
        for (int i = 0; i < 8; ++i) {
            short8 k8 = *(const short8*)(kb + i * 8);
            #pragma unroll
            for (int j = 0; j < 8; ++j) {
                float kf = bf2f(k8[j]);
                #pragma unroll
                for (int t = 0; t < 4; ++t) sc[t] += kf * qlds[t * 64 + i * 8 + j];
            }
        }
        #pragma unroll
        for (int t = 0; t < 4; ++t) {
            float e = __expf(sc[t]);
            Esm[t * 512 + half * 256 + tid] = e;
            lp[t] += e;
        }
    }
    #pragma unroll
    for (int t = 0; t < 4; ++t) {
        float v = lp[t];
        for (int off = 32; off; off >>= 1) v += __shfl_down(v, off);
        if (lane == 0) wl[wid][t] = v;
    }
    __syncthreads();
    if (tid < 4)
        Lpart[((b * 4 + n) * 32 + chunk) * 4 + tid] = wl[0][tid] + wl[1][tid] + wl[2][tid] + wl[3][tid];

    float o = 0.f;
    int tt = tid >> 6, d = tid & 63;
    for (int sub = 0; sub < 4; ++sub) {
        __syncthreads();
        #pragma unroll
        for (int j = 0; j < 4; ++j) {
            int idx = tid + j * 256;
            int r = idx >> 3, c16 = idx & 7;
            const short* vb = KV + (size_t)(b * 16384 + s0 + sub * 128 + r) * 512 + 256 + n * 64 + c16 * 8;
            *(short8*)((char*)vlds + r * 144 + c16 * 16) = *(const short8*)vb;
        }
        __syncthreads();
        #pragma unroll 8
        for (int r = 0; r < 128; ++r)
            o += Esm[tt * 512 + sub * 128 + r] * bf2f(vlds[r * 72 + d]);
    }
    Opart[(size_t)((b * 4 + n) * 32 + chunk) * 256 + tid] = o;
}

__global__ __launch_bounds__(256) void attn_b(const float* Opart, const float* Lpart, float* attended)
{
    int bn = blockIdx.x;
    int tid = threadIdx.x, t = tid >> 6, d = tid & 63;
    float o = 0.f, l = 0.f;
    for (int c = 0; c < 32; ++c) o += Opart[(size_t)(bn * 32 + c) * 256 + tid];
    for (int c = 0; c < 32; ++c) l += Lpart[(bn * 32 + c) * 4 + t];
    int b = bn >> 2, n = bn & 3;
    attended[(t * 4 + b) * 256 + n * 64 + d] = o / l;
}

__global__ __launch_bounds__(256) void film_kernel(const float* attended, const float* opw, const float* opb,
                                                   const float* fw, const float* fb,
                                                   float* Afilm, float* Bfilm)
{
    __shared__ float att[256], st[256];
    int tb = blockIdx.x, tid = threadIdx.x;
    att[tid] = attended[tb * 256 + tid];
    __syncthreads();
    float a = opb[tid];
    for (int j = 0; j < 256; ++j) a += att[j] * opw[tid * 256 + j];
    st[tid] = a;
    __syncthreads();
    float g1 = fb[tid];
    for (int j = 0; j < 256; ++j) g1 += st[j] * fw[tid * 256 + j];
    if (tid < 192) Afilm[tb * 192 + tid] = 1.f + g1;
    else           Bfilm[tb * 192 + (tid - 192)] = g1;
    if (tid < 128) {
        int jj = 256 + tid;
        float g2 = fb[jj];
        for (int j = 0; j < 256; ++j) g2 += st[j] * fw[jj * 256 + j];
        Bfilm[tb * 192 + (jj - 192)] = g2;
    }
}

__global__ __launch_bounds__(256) void make_w2(const short* Wfold, const float* Afilm, short* W2L)
{
    __shared__ float A[192];
    int tb = blockIdx.x, tap = blockIdx.y;
    if (threadIdx.x < 192) A[threadIdx.x] = Afilm[tb * 192 + threadIdx.x];
    __syncthreads();
    for (int u = threadIdx.x; u < 4608; u += 256) {
        int ec = u / 768, rem = u % 768, f16 = rem >> 6, l = rem & 63;
        int f = f16 * 16 + (l & 15), e0 = ec * 32 + (l >> 4) * 8;
        short8 wv = *(const short8*)(Wfold + (tap * 192 + f) * 192 + e0);
        short8 o;
        #pragma unroll
        for (int j = 0; j < 8; ++j) o[j] = f2bf(bf2f(wv[j]) * A[e0 + j]);
        *(short8*)(W2L + ((((size_t)(tb * 6 + ec) * 9 + tap) * 12 + f16) * 64 + l) * 8) = o;
    }
}

__global__ __launch_bounds__(256) void make_btab(const short* Wfold, const float* Bfilm, float* Btab)
{
    __shared__ short Wt[192 * 192];
    __shared__ float Bv[16][192];
    int tap = blockIdx.x, tid = threadIdx.x;
    for (int u = tid; u < 4608; u += 256)
        *(short8*)(Wt + u * 8) = *(const short8*)(Wfold + (size_t)tap * 36864 + u * 8);
    for (int u = tid; u < 3072; u += 256) Bv[u / 192][u % 192] = Bfilm[u];
    __syncthreads();
    for (int o = tid; o < 3072; o += 256) {
        int tb = o / 192, f = o % 192;
        const short* wr = Wt + f * 192;
        float a = 0.f;
        #pragma unroll 8
        for (int e = 0; e < 192; ++e) a += bf2f(wr[e]) * Bv[tb][e];
        Btab[((size_t)tb * 9 + tap) * 192 + f] = a;
    }
}

// conv (R13-proven): 8-wave (512-thread) block, wave tile 48f x 64w (acc[3][4]),
// (512,2) launch bounds — the only spill-free config; occupancy reaches 34%+
// naturally. GLDS staging from P2 planes, per-tap af[3] from coalesced W2L.
__global__ __launch_bounds__(512, 2) void conv2_kernel(const short* P2, const short* W2L, const float* t2,
                                                       const float* Btab, const float* maskf,
                                                       const short* zp, float* out)
{
    __shared__ __align__(16) short XB[2][12480];   // 12 segs * 130 units * 8 shorts
    __shared__ float biasC[192], cLs[192], cRs[192];
    int tid = threadIdx.x, lane = tid & 63, wid = tid >> 6;
    int fgrp = wid >> 1, whalf = wid & 1;
    int i = blockIdx.x + blockIdx.y * 128;
    int n = (i & 7) * 256 + (i >> 3);              // XCD-chunked remap
    int h = n & 127, tb = n >> 7;
    int b = tb & 3;
    float m = maskf[tb];
    float* obase = out + (size_t)tb * 192 * 16384 + h * 128;
    if (m == 0.f) {
        #pragma unroll
        for (int it = 0; it < 48; ++it) {
            int idx = tid + it * 512;
            int f = idx >> 7, w = idx & 127;
            obase[(size_t)f * 16384 + w] = 0.f;
        }
        return;
    }
    if (tid < 192) {
        const float* T = Btab + (size_t)tb * 1728 + tid;
        float s0 = T[0], s1 = T[192], s2v = T[384], s3 = T[576], s4 = T[768];
        float s5 = T[960], s6 = T[1152], s7 = T[1344], s8 = T[1536];
        float bc = s0 + s1 + s2v + s3 + s4 + s5 + s6 + s7 + s8;
        float l = s0 + s3 + s6, r = s2v + s5 + s8;
        if (h == 0)   { bc -= s0 + s1 + s2v; l -= s0; r -= s2v; }
        if (h == 127) { bc -= s6 + s7 + s8; l -= s6; r -= s8; }
        biasC[tid] = bc; cLs[tid] = l; cRs[tid] = r;
    }
    f32x4 acc[3][4];
    #pragma unroll
    for (int a = 0; a < 3; ++a)
        #pragma unroll
        for (int c = 0; c < 4; ++c)
            #pragma unroll
            for (int r = 0; r < 4; ++r) acc[a][c][r] = 0.f;

    short* buf0 = &XB[0][0];
    short* buf1 = &XB[1][0];

    auto STAGE = [&](short* buf, int ec) {
        #pragma unroll
        for (int s = 0; s < 2; ++s) {
            int seg = wid + s * 8;
            if (seg < 12) {
                int row = seg >> 2, eu = seg & 3;
                int habs = h + row - 1;
                bool hok = (unsigned)habs < 128u;
                const short* plane = P2 + ((size_t)(b * 24 + ec * 4 + eu) * 16384) * 8;
                long hbase = (long)habs * 128 - 1;
                short* ldst = buf + seg * 1040;
                const short* a0 = (hok && lane > 0) ? plane + (hbase + lane) * 8       : zp + lane * 8;
                const short* a1 = hok               ? plane + (hbase + 64 + lane) * 8  : zp + 1024 + lane * 8;
                GLDS(a0, ldst);
                GLDS(a1, ldst + 512);
                if (lane < 2) {
                    const short* a2 = (hok && lane < 1) ? plane + (hbase + 128 + lane) * 8 : zp + 2048 + lane * 8;
                    GLDS(a2, ldst + 1024);
                }
            }
        }
    };
    const short* wbase = W2L + (size_t)tb * 331776 + (fgrp * 3) * 512 + lane * 8;
    int cl = lane & 15, q = lane >> 4;

    STAGE(buf0, 0);
    __syncthreads();
    #pragma unroll
    for (int t = 0; t < 6; ++t) {
        const short* cur = (t & 1) ? buf1 : buf0;
        short* nxt = (t & 1) ? buf0 : buf1;
        if (t < 5) STAGE(nxt, t + 1);

        const short* wec = wbase + (size_t)t * 55296;
        __builtin_amdgcn_s_setprio(1);
        #pragma unroll
        for (int tap = 0; tap < 9; ++tap) {
            int dy = tap / 3, dx = tap % 3;
            short8 af[3];
            #pragma unroll
            for (int ft = 0; ft < 3; ++ft)
                af[ft] = *(const short8*)(wec + tap * 6144 + ft * 512);
            const short* xrow = cur + ((dy * 4 + q) * 130 + whalf * 64 + cl + dx) * 8;
            #pragma unroll
            for (int wt = 0; wt < 4; ++wt) {
                short8 xb = *(const short8*)(xrow + wt * 128);
                #pragma unroll
                for (int ft = 0; ft < 3; ++ft)
                    acc[ft][wt] = __builtin_amdgcn_mfma_f32_16x16x32_bf16(af[ft], xb, acc[ft][wt], 0, 0, 0);
            }
        }
        __builtin_amdgcn_s_setprio(0);
        if (t < 5) __syncthreads();
    }

    #pragma unroll
    for (int ft = 0; ft < 3; ++ft)
        #pragma unroll
        for (int r = 0; r < 4; ++r) {
            int f = fgrp * 48 + ft * 16 + q * 4 + r;
            float bc = biasC[f] + t2[f];
            float lf = cLs[f], rg = cRs[f];
            #pragma unroll
            for (int wt = 0; wt < 4; ++wt) {
                int w = whalf * 64 + wt * 16 + cl;
                float val = acc[ft][wt][r] + bc;
                if (w == 0)   val -= lf;
                if (w == 127) val -= rg;
                obase[(size_t)f * 16384 + w] = val / (1.f + __expf(-val)) * m;
            }
        }
}

// ---- fallback conv (used if ws_size too small for W2L), P2 layout ----
__global__ __launch_bounds__(256) void conv_kernel(const short* P2, const short* Wfold, const float* t2,
                                                   const float* Afilm, const float* Bfilm, const float* maskf,
                                                   float* out)
{
    __shared__ short Xs[3 * 130 * 32];
    __shared__ float Af[192], Bf[192];
    int tid = threadIdx.x, lane = tid & 63, wid = tid >> 6;
    int h = blockIdx.x, tb = blockIdx.y;
    int b = tb & 3;
    float* obase = out + (size_t)tb * 192 * 16384 + h * 128;
    float m = maskf[tb];
    if (m == 0.f) {
        #pragma unroll
        for (int i = 0; i < 96; ++i) {
            int idx = tid + i * 256;
            int f = idx >> 7, w = idx & 127;
            obase[(size_t)f * 16384 + w] = 0.f;
        }
        return;
    }
    if (tid < 192) { Af[tid] = Afilm[tb * 192 + tid]; Bf[tid] = Bfilm[tb * 192 + tid]; }
    f32x4 acc[3][8];
    #pragma unroll
    for (int i = 0; i < 3; ++i)
        #pragma unroll
        for (int j = 0; j < 8; ++j)
            #pragma unroll
            for (int r = 0; r < 4; ++r) acc[i][j][r] = 0.f;
    __syncthreads();

    for (int ec = 0; ec < 6; ++ec) {
        #pragma unroll
        for (int it = 0; it < 7; ++it) {
            int u = tid + it * 256;
            if (u < 1560) {
                int pos = u >> 2, half = u & 3;
                int row = (pos >= 260) ? 2 : (pos >= 130 ? 1 : 0);
                int col = pos - row * 130;
                int habs = h + row - 1;
                int w = col - 1;
                short8 x8 = {0, 0, 0, 0, 0, 0, 0, 0};
                if ((unsigned)habs < 128u && (unsigned)w < 128u) {
                    int e0 = ec * 32 + half * 8;
                    short8 pv = *(const short8*)(P2 + ((size_t)(b * 24 + (e0 >> 3)) * 16384 + habs * 128 + w) * 8);
                    #pragma unroll
                    for (int i = 0; i < 8; ++i)
                        x8[i] = f2bf(bf2f(pv[i]) * Af[e0 + i] + Bf[e0 + i]);
                }
                *(short8*)((char*)Xs + (((row * 130 + col) * 64 + half * 16) ^ ((col & 7) << 4))) = x8;
            }
        }
        __syncthreads();
        #pragma unroll
        for (int tap = 0; tap < 9; ++tap) {
            int dy = tap / 3, dx = tap % 3;
            short8 af[3];
            #pragma unroll
            for (int ft = 0; ft < 3; ++ft) {
                int f = wid * 48 + ft * 16 + (lane & 15);
                af[ft] = *(const short8*)(Wfold + (tap * 192 + f) * 192 + ec * 32 + (lane >> 4) * 8);
            }
            #pragma unroll
            for (int wt = 0; wt < 8; ++wt) {
                int cs = wt * 16 + (lane & 15) + dx;
                short8 bfr = *(const short8*)((char*)Xs + (((dy * 130 + cs) * 64 + (lane >> 4) * 16) ^ ((cs & 7) << 4)));
                #pragma unroll
                for (int ft = 0; ft < 3; ++ft)
                    acc[ft][wt] = __builtin_amdgcn_mfma_f32_16x16x32_bf16(af[ft], bfr, acc[ft][wt], 0, 0, 0);
            }
        }
        __syncthreads();
    }
    #pragma unroll
    for (int ft = 0; ft < 3; ++ft)
        #pragma unroll
        for (int wt = 0; wt < 8; ++wt) {
            int w = wt * 16 + (lane & 15);
            #pragma unroll
            for (int r = 0; r < 4; ++r) {
                int f = wid * 48 + ft * 16 + (lane >> 4) * 4 + r;
                float val = acc[ft][wt][r] + t2[f];
                obase[(size_t)f * 16384 + w] = val / (1.f + __expf(-val)) * m;
            }
        }
}

extern "C" void kernel_launch(void* const* d_in, const int* in_sizes, int n_in,
                              void* d_out, int out_size, void* d_ws, size_t ws_size,
                              hipStream_t stream)
{
    (void)in_sizes; (void)n_in; (void)out_size;
    const float* memory = (const float*)d_in[0];
    const void*  mask   = d_in[1];
    const float* sq     = (const float*)d_in[2];
    const float* mpw    = (const float*)d_in[3];
    const float* ipw    = (const float*)d_in[4];
    const float* ipb    = (const float*)d_in[5];
    const float* opw    = (const float*)d_in[6];
    const float* opb    = (const float*)d_in[7];
    const float* evw    = (const float*)d_in[8];
    const float* bn1g   = (const float*)d_in[9];
    const float* bn1b   = (const float*)d_in[10];
    const float* bn1m   = (const float*)d_in[11];
    const float* bn1v   = (const float*)d_in[12];
    const float* gatew  = (const float*)d_in[13];
    const float* gateb  = (const float*)d_in[14];
    const float* filmw  = (const float*)d_in[15];
    const float* filmb  = (const float*)d_in[16];
    const float* outw   = (const float*)d_in[17];
    const float* bn2g   = (const float*)d_in[18];
    const float* bn2b   = (const float*)d_in[19];
    const float* bn2m   = (const float*)d_in[20];
    const float* bn2v   = (const float*)d_in[21];

    char* ws = (char*)d_ws;
    short* P        = (short*)(ws + 65536);            // 25165824 B (P2: [b][24][16384][8])
    short* Wbig     = (short*)(ws + 25296896);         // 458752 B
    float* biasBig  = (float*)(ws + 25755648);         // 3584 B
    short* Wfold    = (short*)(ws + 25759232);         // 663552 B
    float* t2       = (float*)(ws + 26422784);         // 768 B
    float* qs       = (float*)(ws + 26423552);         // 4096 B
    float* attended = (float*)(ws + 26427648);         // 4096 B
    float* Afilm    = (float*)(ws + 26431744);         // 12288 B
    float* Bfilm    = (float*)(ws + 26444032);         // 12288 B
    float* maskf    = (float*)(ws + 26456320);         // 256 B
    float* Lpart    = (float*)(ws + 26456576);         // 8192 B
    short* W2       = (short*)(ws + 26464768);         // 10616832 B (W2L)
    float* Btab     = (float*)(ws + 37081600);         // 110592 B
    const size_t WS_NEED = 37204480;

    char* ob = (char*)d_out;
    short* KV     = (short*)(ob);                      // 67108864 B
    short* memT   = (short*)(ob + 67108864);           // 33554432 B
    float* Opart  = (float*)(ob + 100663296);          // 524288 B

    make_wbig<<<896, 256, 0, stream>>>(evw, bn1g, bn1b, bn1m, bn1v, gatew, gateb, ipw, ipb, mpw, Wbig, biasBig);
    make_wfold<<<208, 256, 0, stream>>>(outw, bn2g, bn2b, bn2m, bn2v, Wfold, t2, (float*)ws);
    make_q<<<5, 256, 0, stream>>>(sq, ipw, ipb, mask, qs, maskf);
    transpose_mem<<<dim3(256, 4, 4), 256, 0, stream>>>(memory, memT);
    big_gemm<<<dim3(128, 7, 4), 256, 0, stream>>>(memT, Wbig, biasBig, P, KV);
    attn_a<<<dim3(32, 4, 4), 256, 0, stream>>>(KV, qs, Opart, Lpart);
    attn_b<<<16, 256, 0, stream>>>(Opart, Lpart, attended);
    film_kernel<<<16, 256, 0, stream>>>(attended, opw, opb, filmw, filmb, Afilm, Bfilm);

    if (ws_size >= WS_NEED) {
        make_w2<<<dim3(16, 9), 256, 0, stream>>>(Wfold, Afilm, W2);
        make_btab<<<9, 256, 0, stream>>>(Wfold, Bfilm, Btab);
        conv2_kernel<<<dim3(128, 16), 512, 0, stream>>>(P, W2, t2, Btab, maskf, (const short*)ws, (float*)d_out);
    } else {
        conv_kernel<<<dim3(128, 16), 256, 0, stream>>>(P, Wfold, t2, Afilm, Bfilm, maskf, (float*)d_out);
    }
}